// Round 1
// baseline (1439.037 us; speedup 1.0000x reference)
//
#include <hip/hip_runtime.h>

#define T_TOT 100
#define BATCH 512
#define FIN   784
#define HID   1024
#define NOUT  10

// ---------------------------------------------------------------------------
// Phase 1: Z[m][n] = sum_k X[m*784+k] * W[n*784+k] + bias[n]
// M = rows (multiple of 128), N = 1024, K = 784. Grid: (M/128)*8 blocks.
// 128x128 block tile, BK=16, 256 threads, 8x8 micro-tile (2x2 blocks of 4x4).
// ---------------------------------------------------------------------------
__global__ __launch_bounds__(256, 4)
void gemm_zin(const float* __restrict__ X, const float* __restrict__ W,
              const float* __restrict__ bias, float* __restrict__ Z)
{
    __shared__ float As[16][132];   // [k][m], stride 132 (16B-aligned rows)
    __shared__ float Bs[16][132];   // [k][n]

    const int tid = threadIdx.x;
    const int tx  = tid & 15;
    const int ty  = tid >> 4;
    const int bm  = blockIdx.x >> 3;
    const int bn  = blockIdx.x & 7;
    const size_t row0 = (size_t)bm * 128;
    const int    col0 = bn * 128;

    const int lrow = tid >> 2;   // 0..63
    const int lkq  = tid & 3;    // k-quad 0..3

    const float* Ap0 = X + (row0 + lrow) * FIN + lkq * 4;
    const float* Ap1 = Ap0 + (size_t)64 * FIN;
    const float* Bp0 = W + (size_t)(col0 + lrow) * FIN + lkq * 4;
    const float* Bp1 = Bp0 + (size_t)64 * FIN;

    float4 ra0 = *(const float4*)Ap0;
    float4 ra1 = *(const float4*)Ap1;
    float4 rb0 = *(const float4*)Bp0;
    float4 rb1 = *(const float4*)Bp1;

    float acc[8][8];
    #pragma unroll
    for (int i = 0; i < 8; ++i)
        #pragma unroll
        for (int j = 0; j < 8; ++j) acc[i][j] = 0.f;

    for (int kt = 0; kt < 49; ++kt) {
        __syncthreads();
        As[lkq*4+0][lrow]    = ra0.x;
        As[lkq*4+1][lrow]    = ra0.y;
        As[lkq*4+2][lrow]    = ra0.z;
        As[lkq*4+3][lrow]    = ra0.w;
        As[lkq*4+0][lrow+64] = ra1.x;
        As[lkq*4+1][lrow+64] = ra1.y;
        As[lkq*4+2][lrow+64] = ra1.z;
        As[lkq*4+3][lrow+64] = ra1.w;
        Bs[lkq*4+0][lrow]    = rb0.x;
        Bs[lkq*4+1][lrow]    = rb0.y;
        Bs[lkq*4+2][lrow]    = rb0.z;
        Bs[lkq*4+3][lrow]    = rb0.w;
        Bs[lkq*4+0][lrow+64] = rb1.x;
        Bs[lkq*4+1][lrow+64] = rb1.y;
        Bs[lkq*4+2][lrow+64] = rb1.z;
        Bs[lkq*4+3][lrow+64] = rb1.w;
        __syncthreads();

        if (kt < 48) {                      // prefetch next K-tile into regs
            const int off = (kt + 1) * 16;
            ra0 = *(const float4*)(Ap0 + off);
            ra1 = *(const float4*)(Ap1 + off);
            rb0 = *(const float4*)(Bp0 + off);
            rb1 = *(const float4*)(Bp1 + off);
        }

        #pragma unroll
        for (int kk = 0; kk < 16; ++kk) {
            float av[8], bv[8];
            *(float4*)&av[0] = *(const float4*)&As[kk][ty*4];
            *(float4*)&av[4] = *(const float4*)&As[kk][ty*4 + 64];
            *(float4*)&bv[0] = *(const float4*)&Bs[kk][tx*4];
            *(float4*)&bv[4] = *(const float4*)&Bs[kk][tx*4 + 64];
            #pragma unroll
            for (int i = 0; i < 8; ++i)
                #pragma unroll
                for (int j = 0; j < 8; ++j)
                    acc[i][j] = fmaf(av[i], bv[j], acc[i][j]);
        }
    }

    float4 bb0 = *(const float4*)&bias[col0 + tx*4];
    float4 bb1 = *(const float4*)&bias[col0 + tx*4 + 64];
    const float bbs[8] = {bb0.x, bb0.y, bb0.z, bb0.w, bb1.x, bb1.y, bb1.z, bb1.w};

    #pragma unroll
    for (int i = 0; i < 8; ++i) {
        const size_t m = row0 + ty*4 + (i>>2)*64 + (i&3);
        #pragma unroll
        for (int jb = 0; jb < 2; ++jb) {
            const int n = col0 + tx*4 + jb*64;
            float4 r;
            r.x = acc[i][jb*4+0] + bbs[jb*4+0];
            r.y = acc[i][jb*4+1] + bbs[jb*4+1];
            r.z = acc[i][jb*4+2] + bbs[jb*4+2];
            r.w = acc[i][jb*4+3] + bbs[jb*4+3];
            *(float4*)&Z[m * HID + n] = r;
        }
    }
}

// ---------------------------------------------------------------------------
// Phase 2: fused LIF + LI scan over a chunk of tn timesteps.
// One block per batch row; each thread owns 4 hidden units in registers.
// Wout (10x1024) staged in LDS. Per-step: LIF update, spike matvec via
// wave shuffle reduce + cross-wave LDS reduce, LI update, write voltage.
// ---------------------------------------------------------------------------
__global__ __launch_bounds__(256, 2)
void lif_scan(const float* __restrict__ Z, const float* __restrict__ Wout,
              float* __restrict__ out,
              float* __restrict__ st_v, float* __restrict__ st_i,
              float* __restrict__ st_vli, float* __restrict__ st_ili,
              int t0, int tn, int first, int last)
{
#pragma clang fp contract(off)   // mirror numpy's unfused mul/add rounding
    __shared__ float Wlds[NOUT][HID];
    __shared__ float red[2][4][NOUT];

    const int tid  = threadIdx.x;
    const int b    = blockIdx.x;
    const int h4   = tid * 4;
    const int lane = tid & 63;
    const int wv   = tid >> 6;

    #pragma unroll
    for (int o = 0; o < NOUT; ++o)
        *(float4*)&Wlds[o][h4] = *(const float4*)&Wout[o * HID + h4];

    float v[4], cu[4];
    if (first) {
        #pragma unroll
        for (int j = 0; j < 4; ++j) { v[j] = 0.f; cu[j] = 0.f; }
    } else {
        float4 tv = *(const float4*)&st_v[(size_t)b*HID + h4];
        float4 ti = *(const float4*)&st_i[(size_t)b*HID + h4];
        v[0]=tv.x; v[1]=tv.y; v[2]=tv.z; v[3]=tv.w;
        cu[0]=ti.x; cu[1]=ti.y; cu[2]=ti.z; cu[3]=ti.w;
    }
    float vli = 0.f, ili = 0.f;
    if (!first && tid < NOUT) {
        vli = st_vli[b*NOUT + tid];
        ili = st_ili[b*NOUT + tid];
    }

    __syncthreads();

    const float* Zb = Z + (size_t)b * HID + h4;
    float4 zn = *(const float4*)Zb;   // prefetch t=0

    for (int t = 0; t < tn; ++t) {
        float4 zc = zn;
        if (t + 1 < tn) zn = *(const float4*)(Zb + (size_t)(t+1) * BATCH * HID);

        const float za[4] = {zc.x, zc.y, zc.z, zc.w};
        float zf[4];
        bool anyz = false;
        #pragma unroll
        for (int j = 0; j < 4; ++j) {
            float tmp  = (0.0f - v[j]) + cu[j];
            float vdec = v[j] + 0.1f * tmp;          // v + dt*tau_mem_inv*((vl-v)+i)
            bool  z    = vdec > 1.0f;                // superspike(v_dec - 1)
            zf[j] = z ? 1.0f : 0.0f;
            anyz  = anyz || z;
            v[j]  = z ? 0.0f : vdec;                 // reset to 0
            cu[j] = cu[j] * 0.8f + za[j];            // i*(1-dt*tau_syn_inv) + z_in
        }

        float p[NOUT];
        #pragma unroll
        for (int o = 0; o < NOUT; ++o) p[o] = 0.f;

        if (__any(anyz)) {                           // skip silent waves
            if (anyz) {
                #pragma unroll
                for (int o = 0; o < NOUT; ++o) {
                    float4 w = *(const float4*)&Wlds[o][h4];
                    p[o] = zf[0]*w.x + zf[1]*w.y + zf[2]*w.z + zf[3]*w.w;
                }
            }
            #pragma unroll
            for (int o = 0; o < NOUT; ++o) {         // wave-64 butterfly reduce
                float s = p[o];
                s += __shfl_xor(s, 1);
                s += __shfl_xor(s, 2);
                s += __shfl_xor(s, 4);
                s += __shfl_xor(s, 8);
                s += __shfl_xor(s, 16);
                s += __shfl_xor(s, 32);
                p[o] = s;
            }
        }

        const int par = t & 1;
        if (lane == 0) {
            #pragma unroll
            for (int o = 0; o < NOUT; ++o) red[par][wv][o] = p[o];
        }
        __syncthreads();
        if (tid < NOUT) {
            float s = red[par][0][tid] + red[par][1][tid]
                    + red[par][2][tid] + red[par][3][tid];
            float tmp  = (0.0f - vli) + ili;
            float vnew = vli + 0.1f * tmp;           // LI voltage (uses OLD i_li)
            ili = ili * 0.8f + s;                    // LI current
            vli = vnew;
            out[((size_t)(t0 + t) * BATCH + b) * NOUT + tid] = vnew;
        }
    }

    if (!last) {
        *(float4*)&st_v[(size_t)b*HID + h4] = make_float4(v[0], v[1], v[2], v[3]);
        *(float4*)&st_i[(size_t)b*HID + h4] = make_float4(cu[0], cu[1], cu[2], cu[3]);
        if (tid < NOUT) { st_vli[b*NOUT + tid] = vli; st_ili[b*NOUT + tid] = ili; }
    }
}

// ---------------------------------------------------------------------------
extern "C" void kernel_launch(void* const* d_in, const int* in_sizes, int n_in,
                              void* d_out, int out_size, void* d_ws, size_t ws_size,
                              hipStream_t stream)
{
    const float* x    = (const float*)d_in[0];   // [100, 512, 784]
    const float* W0   = (const float*)d_in[1];   // [1024, 784]
    const float* b0   = (const float*)d_in[2];   // [1024]
    const float* Wout = (const float*)d_in[3];   // [10, 1024]
    float* out = (float*)d_out;                  // [100, 512, 10]

    float* ws     = (float*)d_ws;
    float* st_v   = ws;                          // 512*1024
    float* st_i   = st_v   + (size_t)BATCH*HID;  // 512*1024
    float* st_vli = st_i   + (size_t)BATCH*HID;  // 512*10
    float* st_ili = st_vli + (size_t)BATCH*NOUT; // 512*10
    float* Zbuf   = st_ili + (size_t)BATCH*NOUT;

    const size_t state_floats = (size_t)BATCH*HID*2 + (size_t)BATCH*NOUT*2;
    const size_t total_floats = ws_size / sizeof(float);
    size_t avail = (total_floats > state_floats) ? total_floats - state_floats : 0;
    int tch = (int)(avail / ((size_t)BATCH * HID));
    if (tch > T_TOT) tch = T_TOT;
    if (tch < 1)     tch = 1;   // assumes ws_size >= ~6.5 MB

    for (int t0 = 0; t0 < T_TOT; t0 += tch) {
        const int tn = (T_TOT - t0 < tch) ? (T_TOT - t0) : tch;
        const int mblocks = (tn * BATCH) / 128;   // tn*4
        hipLaunchKernelGGL(gemm_zin, dim3(mblocks * 8), dim3(256), 0, stream,
                           x + (size_t)t0 * BATCH * FIN, W0, b0, Zbuf);
        hipLaunchKernelGGL(lif_scan, dim3(BATCH), dim3(256), 0, stream,
                           Zbuf, Wout, out, st_v, st_i, st_vli, st_ili,
                           t0, tn, (t0 == 0) ? 1 : 0, (t0 + tn >= T_TOT) ? 1 : 0);
    }
}

// Round 2
// 537.359 us; speedup vs baseline: 2.6780x; 2.6780x over previous
//
#include <hip/hip_runtime.h>

#define T_TOT 100
#define BATCH 512
#define FIN   784
#define HID   1024
#define NOUT  10
#define KP    800      // K padded to multiple of 32
#define BK    32
#define KSTEPS 25      // KP / BK

typedef _Float16 f16x8 __attribute__((ext_vector_type(8)));
typedef float    f32x4 __attribute__((ext_vector_type(4)));

#define AS1C(p) ((const __attribute__((address_space(1))) void*)(p))
#define AS3(p)  ((__attribute__((address_space(3))) void*)(p))

// ---------------------------------------------------------------------------
// fp32 -> fp16 hi/lo split, row length 784 padded to 800.
//   hi = fp16(x);  lo = fp16((x - hi) * 4096)   (scaling avoids fp16 denorms)
// One thread per 8 k's: idx -> (row, k0).
// ---------------------------------------------------------------------------
__global__ __launch_bounds__(256)
void cvt_split(const float* __restrict__ src, _Float16* __restrict__ hi,
               _Float16* __restrict__ lo, int nrows)
{
    int idx = blockIdx.x * 256 + threadIdx.x;
    if (idx >= nrows * 100) return;
    int row = idx / 100;
    int k0  = (idx - row * 100) * 8;
    f16x8 h, l;
    if (k0 < FIN) {
        float4 a = *(const float4*)(src + (size_t)row * FIN + k0);
        float4 b = *(const float4*)(src + (size_t)row * FIN + k0 + 4);
        float xs[8] = {a.x, a.y, a.z, a.w, b.x, b.y, b.z, b.w};
        #pragma unroll
        for (int j = 0; j < 8; ++j) {
            _Float16 hh = (_Float16)xs[j];
            h[j] = hh;
            l[j] = (_Float16)((xs[j] - (float)hh) * 4096.0f);
        }
    } else {
        #pragma unroll
        for (int j = 0; j < 8; ++j) { h[j] = (_Float16)0.f; l[j] = (_Float16)0.f; }
    }
    *(f16x8*)(hi + (size_t)row * KP + k0) = h;
    *(f16x8*)(lo + (size_t)row * KP + k0) = l;
}

// ---------------------------------------------------------------------------
// Z = Xsplit · Wsplit^T + bias   via fp16 MFMA, 3 terms:
//   accm += Ahi*Bhi ;  accc += Ahi*Blo' + Alo'*Bhi ;  Z = accm + accc/4096 + b
// 128x128 tile, BK=32, 256 thr = 4 waves (2x2), each wave 64x64 (4x4 frags).
// LDS: 4 tiles x 8KB, double buffered = 64KB. global_load_lds width 16 with
// chunk XOR-swizzle (g ^= (row>>1)&3) applied on BOTH source addr and ds_read.
// ---------------------------------------------------------------------------
__global__ __launch_bounds__(256, 2)
void gemm_mfma(const _Float16* __restrict__ Xhi, const _Float16* __restrict__ Xlo,
               const _Float16* __restrict__ Whi, const _Float16* __restrict__ Wlo,
               const float* __restrict__ bias, float* __restrict__ Z, int mb)
{
    __shared__ char smem[65536];
    const int tid  = threadIdx.x;
    const int lane = tid & 63;
    const int wid  = tid >> 6;
    const int wm   = wid >> 1;
    const int wn   = wid & 1;
    const int fr   = lane & 15;   // fragment row (A) / col (B) / out col
    const int fg   = lane >> 4;   // k-group / out row quad

    const int j = blockIdx.x;
    int bm, bn;
    if ((mb & 7) == 0) {          // XCD-friendly: all 8 bn of a bm share blockIdx%8
        bm = (j & 7) | ((j >> 6) << 3);
        bn = (j >> 3) & 7;
    } else {
        bm = j >> 3;
        bn = j & 7;
    }
    const size_t row0 = (size_t)bm * 128;
    const int    col0 = bn * 128;

    f32x4 accm[4][4], accc[4][4];
    #pragma unroll
    for (int a = 0; a < 4; ++a)
        #pragma unroll
        for (int b = 0; b < 4; ++b) {
            accm[a][b] = (f32x4){0.f, 0.f, 0.f, 0.f};
            accc[a][b] = (f32x4){0.f, 0.f, 0.f, 0.f};
        }

    auto stage = [&](int buf, int kt) {
        const int kof = kt * BK;
        #pragma unroll
        for (int q = 0; q < 2; ++q) {
            const int lin = q * 256 + tid;       // 0..511 16B slots
            const int row = lin >> 2;            // 0..127
            const int pos = lin & 3;             // chunk slot in LDS
            const int gg  = pos ^ ((row >> 1) & 3);  // logical k-chunk (inverse swz)
            const int ldsw = buf * 32768 + q * 4096 + wid * 1024;
            const size_t ga = (row0 + row) * (size_t)KP + kof + gg * 8;
            const size_t gb = (size_t)(col0 + row) * KP + kof + gg * 8;
            __builtin_amdgcn_global_load_lds(AS1C(Xhi + ga), AS3(smem + ldsw),         16, 0, 0);
            __builtin_amdgcn_global_load_lds(AS1C(Xlo + ga), AS3(smem + ldsw +  8192), 16, 0, 0);
            __builtin_amdgcn_global_load_lds(AS1C(Whi + gb), AS3(smem + ldsw + 16384), 16, 0, 0);
            __builtin_amdgcn_global_load_lds(AS1C(Wlo + gb), AS3(smem + ldsw + 24576), 16, 0, 0);
        }
    };

    auto compute = [&](int buf) {
        const char* base = smem + buf * 32768;
        f16x8 ah[4], al[4], bh[4], bl[4];
        #pragma unroll
        for (int mf = 0; mf < 4; ++mf) {
            const int row = wm * 64 + mf * 16 + fr;
            const int off = row * 64 + ((fg ^ ((row >> 1) & 3)) << 4);
            ah[mf] = *(const f16x8*)(base + off);
            al[mf] = *(const f16x8*)(base + 8192 + off);
        }
        #pragma unroll
        for (int nf = 0; nf < 4; ++nf) {
            const int row = wn * 64 + nf * 16 + fr;
            const int off = row * 64 + ((fg ^ ((row >> 1) & 3)) << 4);
            bh[nf] = *(const f16x8*)(base + 16384 + off);
            bl[nf] = *(const f16x8*)(base + 24576 + off);
        }
        #pragma unroll
        for (int mf = 0; mf < 4; ++mf)
            #pragma unroll
            for (int nf = 0; nf < 4; ++nf) {
                accm[mf][nf] = __builtin_amdgcn_mfma_f32_16x16x32_f16(ah[mf], bh[nf], accm[mf][nf], 0, 0, 0);
                accc[mf][nf] = __builtin_amdgcn_mfma_f32_16x16x32_f16(ah[mf], bl[nf], accc[mf][nf], 0, 0, 0);
                accc[mf][nf] = __builtin_amdgcn_mfma_f32_16x16x32_f16(al[mf], bh[nf], accc[mf][nf], 0, 0, 0);
            }
    };

    stage(0, 0);
    int buf = 0;
    for (int kt = 0; kt < KSTEPS; ++kt) {
        __syncthreads();                       // drains vmcnt -> buf ready
        if (kt + 1 < KSTEPS) stage(buf ^ 1, kt + 1);
        compute(buf);
        buf ^= 1;
    }

    #pragma unroll
    for (int nf = 0; nf < 4; ++nf) {
        const int colg = col0 + wn * 64 + nf * 16 + fr;
        const float bv = bias[colg];
        #pragma unroll
        for (int mf = 0; mf < 4; ++mf) {
            const size_t rowg = row0 + wm * 64 + mf * 16 + fg * 4;
            #pragma unroll
            for (int i = 0; i < 4; ++i)
                Z[(rowg + i) * HID + colg] =
                    accm[mf][nf][i] + accc[mf][nf][i] * 2.44140625e-4f + bv;
        }
    }
}

// ---------------------------------------------------------------------------
// Fused LIF + LI scan (unchanged from round 1 — passing).
// ---------------------------------------------------------------------------
__global__ __launch_bounds__(256, 2)
void lif_scan(const float* __restrict__ Z, const float* __restrict__ Wout,
              float* __restrict__ out,
              float* __restrict__ st_v, float* __restrict__ st_i,
              float* __restrict__ st_vli, float* __restrict__ st_ili,
              int t0, int tn, int first, int last)
{
#pragma clang fp contract(off)   // mirror numpy's unfused mul/add rounding
    __shared__ float Wlds[NOUT][HID];
    __shared__ float red[2][4][NOUT];

    const int tid  = threadIdx.x;
    const int b    = blockIdx.x;
    const int h4   = tid * 4;
    const int lane = tid & 63;
    const int wv   = tid >> 6;

    #pragma unroll
    for (int o = 0; o < NOUT; ++o)
        *(float4*)&Wlds[o][h4] = *(const float4*)&Wout[o * HID + h4];

    float v[4], cu[4];
    if (first) {
        #pragma unroll
        for (int j = 0; j < 4; ++j) { v[j] = 0.f; cu[j] = 0.f; }
    } else {
        float4 tv = *(const float4*)&st_v[(size_t)b*HID + h4];
        float4 ti = *(const float4*)&st_i[(size_t)b*HID + h4];
        v[0]=tv.x; v[1]=tv.y; v[2]=tv.z; v[3]=tv.w;
        cu[0]=ti.x; cu[1]=ti.y; cu[2]=ti.z; cu[3]=ti.w;
    }
    float vli = 0.f, ili = 0.f;
    if (!first && tid < NOUT) {
        vli = st_vli[b*NOUT + tid];
        ili = st_ili[b*NOUT + tid];
    }

    __syncthreads();

    const float* Zb = Z + (size_t)b * HID + h4;
    float4 zn = *(const float4*)Zb;   // prefetch t=0

    for (int t = 0; t < tn; ++t) {
        float4 zc = zn;
        if (t + 1 < tn) zn = *(const float4*)(Zb + (size_t)(t+1) * BATCH * HID);

        const float za[4] = {zc.x, zc.y, zc.z, zc.w};
        float zf[4];
        bool anyz = false;
        #pragma unroll
        for (int j = 0; j < 4; ++j) {
            float tmp  = (0.0f - v[j]) + cu[j];
            float vdec = v[j] + 0.1f * tmp;
            bool  z    = vdec > 1.0f;
            zf[j] = z ? 1.0f : 0.0f;
            anyz  = anyz || z;
            v[j]  = z ? 0.0f : vdec;
            cu[j] = cu[j] * 0.8f + za[j];
        }

        float p[NOUT];
        #pragma unroll
        for (int o = 0; o < NOUT; ++o) p[o] = 0.f;

        if (__any(anyz)) {
            if (anyz) {
                #pragma unroll
                for (int o = 0; o < NOUT; ++o) {
                    float4 w = *(const float4*)&Wlds[o][h4];
                    p[o] = zf[0]*w.x + zf[1]*w.y + zf[2]*w.z + zf[3]*w.w;
                }
            }
            #pragma unroll
            for (int o = 0; o < NOUT; ++o) {
                float s = p[o];
                s += __shfl_xor(s, 1);
                s += __shfl_xor(s, 2);
                s += __shfl_xor(s, 4);
                s += __shfl_xor(s, 8);
                s += __shfl_xor(s, 16);
                s += __shfl_xor(s, 32);
                p[o] = s;
            }
        }

        const int par = t & 1;
        if (lane == 0) {
            #pragma unroll
            for (int o = 0; o < NOUT; ++o) red[par][wv][o] = p[o];
        }
        __syncthreads();
        if (tid < NOUT) {
            float s = red[par][0][tid] + red[par][1][tid]
                    + red[par][2][tid] + red[par][3][tid];
            float tmp  = (0.0f - vli) + ili;
            float vnew = vli + 0.1f * tmp;
            ili = ili * 0.8f + s;
            vli = vnew;
            out[((size_t)(t0 + t) * BATCH + b) * NOUT + tid] = vnew;
        }
    }

    if (!last) {
        *(float4*)&st_v[(size_t)b*HID + h4] = make_float4(v[0], v[1], v[2], v[3]);
        *(float4*)&st_i[(size_t)b*HID + h4] = make_float4(cu[0], cu[1], cu[2], cu[3]);
        if (tid < NOUT) { st_vli[b*NOUT + tid] = vli; st_ili[b*NOUT + tid] = ili; }
    }
}

// ---------------------------------------------------------------------------
extern "C" void kernel_launch(void* const* d_in, const int* in_sizes, int n_in,
                              void* d_out, int out_size, void* d_ws, size_t ws_size,
                              hipStream_t stream)
{
    const float* x    = (const float*)d_in[0];   // [100, 512, 784]
    const float* W0   = (const float*)d_in[1];   // [1024, 784]
    const float* b0   = (const float*)d_in[2];   // [1024]
    const float* Wout = (const float*)d_in[3];   // [10, 1024]
    float* out = (float*)d_out;                  // [100, 512, 10]

    char* ws = (char*)d_ws;
    float* st_v   = (float*)ws;                          // 512*1024
    float* st_i   = st_v   + (size_t)BATCH * HID;        // 512*1024
    float* st_vli = st_i   + (size_t)BATCH * HID;        // 512*10
    float* st_ili = st_vli + BATCH * NOUT;               // 512*10
    _Float16* Whi = (_Float16*)(st_ili + BATCH * NOUT);  // 1024*800
    _Float16* Wlo = Whi + (size_t)HID * KP;              // 1024*800
    char* dyn = (char*)(Wlo + (size_t)HID * KP);

    const size_t fixed = (size_t)(dyn - ws);
    const size_t per_t = (size_t)BATCH * HID * 4          // Zbuf
                       + (size_t)BATCH * KP * 2 * 2;      // Xhi + Xlo
    size_t avail = (ws_size > fixed) ? ws_size - fixed : 0;
    int tch = (int)(avail / per_t);
    if (tch > T_TOT) tch = T_TOT;
    if (tch >= 2) tch &= ~1;          // keep mb % 8 == 0 for the XCD swizzle
    if (tch < 1) tch = 1;

    float*    Zbuf = (float*)dyn;
    _Float16* Xhi  = (_Float16*)(dyn + (size_t)tch * BATCH * HID * 4);
    _Float16* Xlo  = Xhi + (size_t)tch * BATCH * KP;

    // W conversion once
    hipLaunchKernelGGL(cvt_split, dim3((HID * 100 + 255) / 256), dim3(256), 0, stream,
                       W0, Whi, Wlo, HID);

    for (int t0 = 0; t0 < T_TOT; t0 += tch) {
        const int tn    = (T_TOT - t0 < tch) ? (T_TOT - t0) : tch;
        const int nrows = tn * BATCH;
        const int mb    = nrows / 128;

        hipLaunchKernelGGL(cvt_split, dim3((nrows * 100 + 255) / 256), dim3(256), 0, stream,
                           x + (size_t)t0 * BATCH * FIN, Xhi, Xlo, nrows);
        hipLaunchKernelGGL(gemm_mfma, dim3(mb * 8), dim3(256), 0, stream,
                           Xhi, Xlo, Whi, Wlo, b0, Zbuf, mb);
        hipLaunchKernelGGL(lif_scan, dim3(BATCH), dim3(256), 0, stream,
                           Zbuf, Wout, out, st_v, st_i, st_vli, st_ili,
                           t0, tn, (t0 == 0) ? 1 : 0, (t0 + tn >= T_TOT) ? 1 : 0);
    }
}